// Round 1
// baseline (1620.946 us; speedup 1.0000x reference)
//
#include <hip/hip_runtime.h>
#include <hip/hip_bf16.h>

// Dims: B=64, T=512, V=512, H=256, O=512. M1 = B*T = 32768.
// d_in: sentence, prev_state, W_ih, b_ih, W_hh, b_hh, W_out, b_out
// d_out: tags [B,T,O] fp32 (16777216) then h_n [1,B,H] fp32 (16384)
//
// This round: single "mega" kernel pipelines gemm1 -> rnn -> gemm3.
//   blocks 0-3   : rnn (unchanged inner loop) + chunk waits + progress publish
//   blocks 4-255 : 252 workers: gemm1 tiles (chunk-0 first), then gemm3 tiles
//                  gated on rnn progress flags.
// Cross-XCD visibility via agent-scope acquire/release atomics + __threadfence.

typedef __attribute__((ext_vector_type(8))) _Float16 half8;
typedef __attribute__((ext_vector_type(4))) _Float16 half4;
typedef __attribute__((ext_vector_type(4))) float   floatx4;

// LDS-only barrier: waits LDS ops, does NOT drain vmcnt — global loads/stores
// stay in flight across it.
__device__ __forceinline__ void lds_barrier() {
    asm volatile("s_waitcnt lgkmcnt(0)\n\ts_barrier" ::: "memory");
}

// Single-thread spin with backoff; capped so a logic bug fails verification
// instead of hanging the harness.
__device__ __forceinline__ void wait_ge(int* p, int need) {
    int spin = 0;
    while (__hip_atomic_load(p, __ATOMIC_ACQUIRE, __HIP_MEMORY_SCOPE_AGENT) < need) {
        __builtin_amdgcn_s_sleep(8);
        if (++spin > (1 << 22)) break;
    }
}

// ---------------- fp32 -> fp16 convert (vector4) ----------------
__global__ void conv_f32_f16(const float* __restrict__ in, _Float16* __restrict__ out, int n4) {
    int idx = blockIdx.x * blockDim.x + threadIdx.x;
    if (idx >= n4) return;
    float4 v = ((const float4*)in)[idx];
    half4 h = { (_Float16)v.x, (_Float16)v.y, (_Float16)v.z, (_Float16)v.w };
    ((half4*)out)[idx] = h;
}

// ---------------- mega: gemm1 || rnn || gemm3 ----------------
__global__ __launch_bounds__(512, 2) void mega(
    const float* __restrict__ sentence,      // [32768,512] fp32
    const _Float16* __restrict__ wih,        // [256,512] f16
    const float* __restrict__ b_ih,
    const float* __restrict__ b_hh,
    float* __restrict__ xproj,               // [32768,256] fp32 (bias incl.)
    const float* __restrict__ h0g,           // [1,64,256] fp32
    const float* __restrict__ W_hh,          // [256,256] fp32
    _Float16* __restrict__ hid,              // [32768,256] f16 capped
    float* __restrict__ h_n,                 // [64,256] fp32
    const _Float16* __restrict__ wout,       // [512,256] f16
    const float* __restrict__ b_out,
    float* __restrict__ tags,                // [32768,512] fp32
    int* __restrict__ flags)                 // [0..3]=g1done per t-chunk, [32..35]=rnnprog
{
    int* g1done  = flags;        // gemm1 tiles finished per 128-t chunk (target 64)
    int* rnnprog = flags + 32;   // steps completed per rnn block (separate 128B line)

    const int wave = threadIdx.x >> 6;
    const int lane = threadIdx.x & 63;
    const int row  = lane & 15;
    const int quad = lane >> 4;

    __shared__ _Float16 hb[2][16][264];

    if (blockIdx.x < 4) {
        // ================= RNN role (blocks 0-3) =================
        const int Hh = 256, T = 512, LD = 264;
        int b0 = blockIdx.x * 16;
        int c = row;
        int q = quad;

        // W_hh fragments: wf[nt][kt], n = (wave*2+nt)*16 + c, k = kt*32 + q*8
        half8 wf[2][8];
#pragma unroll
        for (int nt = 0; nt < 2; nt++) {
            int n = (wave * 2 + nt) * 16 + c;
            const float* wr = W_hh + (size_t)n * Hh + q * 8;
#pragma unroll
            for (int kt = 0; kt < 8; kt++) {
                float4 x0 = *(const float4*)(wr + kt * 32);
                float4 x1 = *(const float4*)(wr + kt * 32 + 4);
                wf[nt][kt] = (half8){ (_Float16)x0.x, (_Float16)x0.y, (_Float16)x0.z, (_Float16)x0.w,
                                      (_Float16)x1.x, (_Float16)x1.y, (_Float16)x1.z, (_Float16)x1.w };
            }
        }

        for (int idx = threadIdx.x; idx < 16 * 256; idx += 512) {
            int m = idx >> 8, k = idx & 255;
            hb[0][m][k] = (_Float16)h0g[(size_t)(b0 + m) * Hh + k];
        }
        // Gate first prefetch (t=0,1) on gemm1 chunk 0; one spinner, then barrier
        // (also serves as the hb-fill barrier).
        if (threadIdx.x == 0) wait_ge(&g1done[0], 64);
        __syncthreads();

        const float* xpb = xproj + (size_t)(b0 + c) * T * Hh;
        _Float16* hidb = hid + (size_t)(b0 + c) * T * Hh;

        int noff[2];
#pragma unroll
        for (int nt = 0; nt < 2; nt++) noff[nt] = (wave * 2 + nt) * 16 + q * 4;

        float4 xq0[2], xq1[2];
#pragma unroll
        for (int nt = 0; nt < 2; nt++) {
            xq0[nt] = *(const float4*)(xpb + (size_t)0 * Hh + noff[nt]);
            xq1[nt] = *(const float4*)(xpb + (size_t)1 * Hh + noff[nt]);
        }

        auto do_step = [&](int t, float4 (&xq)[2]) {
            const _Float16* hr = &hb[t & 1][0][0];
            floatx4 aA0 = {0.f,0.f,0.f,0.f}, aA1 = {0.f,0.f,0.f,0.f};
            floatx4 aB0 = {0.f,0.f,0.f,0.f}, aB1 = {0.f,0.f,0.f,0.f};
#pragma unroll
            for (int kt = 0; kt < 4; kt++) {
                half8 hfA = *(const half8*)(hr + c * LD + kt * 32 + q * 8);
                half8 hfB = *(const half8*)(hr + c * LD + (kt + 4) * 32 + q * 8);
                aA0 = __builtin_amdgcn_mfma_f32_16x16x32_f16(wf[0][kt],     hfA, aA0, 0, 0, 0);
                aB0 = __builtin_amdgcn_mfma_f32_16x16x32_f16(wf[0][kt + 4], hfB, aB0, 0, 0, 0);
                aA1 = __builtin_amdgcn_mfma_f32_16x16x32_f16(wf[1][kt],     hfA, aA1, 0, 0, 0);
                aB1 = __builtin_amdgcn_mfma_f32_16x16x32_f16(wf[1][kt + 4], hfB, aB1, 0, 0, 0);
            }
            floatx4 acc[2];
            acc[0] = aA0 + aB0;
            acc[1] = aA1 + aB1;

            _Float16* hw = &hb[(t + 1) & 1][0][0];
#pragma unroll
            for (int nt = 0; nt < 2; nt++) {
                float v0 = fmaxf(acc[nt][0] + xq[nt].x, 0.f);
                float v1 = fmaxf(acc[nt][1] + xq[nt].y, 0.f);
                float v2 = fmaxf(acc[nt][2] + xq[nt].z, 0.f);
                float v3 = fmaxf(acc[nt][3] + xq[nt].w, 0.f);
                half4 hv = { (_Float16)v0, (_Float16)v1, (_Float16)v2, (_Float16)v3 };
                *(half4*)(hw + c * LD + noff[nt]) = hv;
                half4 hc = { (_Float16)fminf(v0, 1.f), (_Float16)fminf(v1, 1.f),
                             (_Float16)fminf(v2, 1.f), (_Float16)fminf(v3, 1.f) };
                *(half4*)(hidb + (size_t)t * Hh + noff[nt]) = hc;
                if (t == T - 1) {
                    float4 hn = { v0, v1, v2, v3 };
                    *(float4*)(h_n + (size_t)(b0 + c) * Hh + noff[nt]) = hn;
                }
            }
            int tp = (t + 2 < T) ? t + 2 : T - 1;
            // crossing into a new 128-t xproj chunk: tp in {128,129,256,257,384,385}
            if ((tp & 126) == 0) {
                if (threadIdx.x == 0) wait_ge(&g1done[tp >> 7], 64);
                __syncthreads();
            }
#pragma unroll
            for (int nt = 0; nt < 2; nt++)
                xq[nt] = *(const float4*)(xpb + (size_t)tp * Hh + noff[nt]);

            lds_barrier();
        };

        for (int t = 0; t < T; t += 2) {
            do_step(t,     xq0);
            do_step(t + 1, xq1);
            if (((t + 2) & 127) == 0) {
                // publish: steps [0, t+2) done, hid rows visible device-wide
                __threadfence();
                __syncthreads();
                if (threadIdx.x == 0)
                    __hip_atomic_store(&rnnprog[blockIdx.x], t + 2,
                                       __ATOMIC_RELEASE, __HIP_MEMORY_SCOPE_AGENT);
            }
        }
    } else {
        // ================= worker role (blocks 4-255) =================
        int w = blockIdx.x - 4;   // 0..251

        // ---- GEMM1: xproj tiles, 128 rows x 256 cols, chunk-0-first order ----
        // work index qq -> chunk = qq>>6, b = qq&63, tile = b*4 + chunk
        const int K1 = 512, N1 = 256;
        for (int qq = w; qq < 256; qq += 252) {
            int chunk = qq >> 6;
            int item  = (qq & 63) * 4 + chunk;
            int m0 = item * 128 + wave * 16;

            floatx4 acc[16];
#pragma unroll
            for (int i = 0; i < 16; i++) acc[i] = (floatx4){0.f, 0.f, 0.f, 0.f};

            const float* pa = sentence + (size_t)(m0 + row) * K1 + quad * 8;
            for (int k0 = 0; k0 < K1; k0 += 32) {
                float4 a0 = *(const float4*)(pa + k0);
                float4 a1 = *(const float4*)(pa + k0 + 4);
                half8 a = { (_Float16)a0.x, (_Float16)a0.y, (_Float16)a0.z, (_Float16)a0.w,
                            (_Float16)a1.x, (_Float16)a1.y, (_Float16)a1.z, (_Float16)a1.w };
#pragma unroll
                for (int nt = 0; nt < 16; nt++) {
                    const _Float16* pb = wih + (size_t)(nt * 16 + row) * K1 + quad * 8 + k0;
                    half8 b = *(const half8*)pb;
                    acc[nt] = __builtin_amdgcn_mfma_f32_16x16x32_f16(a, b, acc[nt], 0, 0, 0);
                }
            }
#pragma unroll
            for (int nt = 0; nt < 16; nt++) {
                int n = nt * 16 + row;
                float bn = b_ih[n] + b_hh[n];
#pragma unroll
                for (int r = 0; r < 4; r++) {
                    int m = m0 + quad * 4 + r;
                    xproj[(size_t)m * N1 + n] = acc[nt][r] + bn;
                }
            }
            __threadfence();          // make this tile's stores agent-visible
            __syncthreads();          // all waves of the block done
            if (threadIdx.x == 0)
                __hip_atomic_fetch_add(&g1done[chunk], 1,
                                       __ATOMIC_RELEASE, __HIP_MEMORY_SCOPE_AGENT);
        }

        // ---- GEMM3: tags tiles, 128 rows x 256 cols, t-chunk-major order ----
        // j -> tc = j>>7 (t-chunk), b = (j&127)>>1, nhalf = j&1
        const int K3 = 256, N3 = 512;
        for (int j = w; j < 512; j += 252) {
            int tc = j >> 7;
            int rr = j & 127;
            int bb = rr >> 1;
            int nh = rr & 1;

            if (threadIdx.x == 0) wait_ge(&rnnprog[bb >> 4], (tc + 1) * 128);
            __syncthreads();

            int m0 = bb * 512 + tc * 128 + wave * 16;
            int n_base = nh * 256;

            floatx4 acc[16];
#pragma unroll
            for (int i = 0; i < 16; i++) acc[i] = (floatx4){0.f, 0.f, 0.f, 0.f};

            const _Float16* pa = hid + (size_t)(m0 + row) * K3 + quad * 8;
            for (int k0 = 0; k0 < K3; k0 += 32) {
                half8 a = *(const half8*)(pa + k0);
#pragma unroll
                for (int nt = 0; nt < 16; nt++) {
                    const _Float16* pb = wout + (size_t)(n_base + nt * 16 + row) * K3 + quad * 8 + k0;
                    half8 b = *(const half8*)pb;
                    acc[nt] = __builtin_amdgcn_mfma_f32_16x16x32_f16(a, b, acc[nt], 0, 0, 0);
                }
            }
#pragma unroll
            for (int nt = 0; nt < 16; nt++) {
                int n = n_base + nt * 16 + row;
                float bn = b_out[n];
#pragma unroll
                for (int r = 0; r < 4; r++) {
                    int m = m0 + quad * 4 + r;
                    float v = acc[nt][r] + bn;
                    tags[(size_t)m * N3 + n] = 1.f / (1.f + __expf(-v));
                }
            }
        }
    }
}

extern "C" void kernel_launch(void* const* d_in, const int* in_sizes, int n_in,
                              void* d_out, int out_size, void* d_ws, size_t ws_size,
                              hipStream_t stream) {
    const float* sentence   = (const float*)d_in[0];  // [64,512,512]
    const float* prev_state = (const float*)d_in[1];  // [1,64,256]
    const float* W_ih       = (const float*)d_in[2];  // [256,512]
    const float* b_ih       = (const float*)d_in[3];  // [256]
    const float* W_hh       = (const float*)d_in[4];  // [256,256]
    const float* b_hh       = (const float*)d_in[5];  // [256]
    const float* W_out      = (const float*)d_in[6];  // [512,256]
    const float* b_out      = (const float*)d_in[7];  // [512]

    const size_t WIH_N   = 256u * 512u;
    const size_t WOUT_N  = 512u * 256u;
    const size_t XPROJ_N = 32768u * 256u;
    const size_t HID_N   = 64u * 512u * 256u;

    char* w = (char*)d_ws;
    _Float16* wih_f  = (_Float16*)w;  w += WIH_N * sizeof(_Float16);
    _Float16* wout_f = (_Float16*)w;  w += WOUT_N * sizeof(_Float16);
    float*    xproj  = (float*)w;     w += XPROJ_N * sizeof(float);
    _Float16* hid_f  = (_Float16*)w;  w += HID_N * sizeof(_Float16);
    int*      flags  = (int*)w;       w += 256;

    float* tags = (float*)d_out;
    float* h_n  = (float*)d_out + 16777216;

    hipMemsetAsync(flags, 0, 256, stream);

    conv_f32_f16<<<(int)(WIH_N / 4 / 256),  256, 0, stream>>>(W_ih,  wih_f,  (int)(WIH_N / 4));
    conv_f32_f16<<<(int)(WOUT_N / 4 / 256), 256, 0, stream>>>(W_out, wout_f, (int)(WOUT_N / 4));

    mega<<<256, 512, 0, stream>>>(sentence, wih_f, b_ih, b_hh, xproj,
                                  prev_state, W_hh, hid_f, h_n,
                                  wout_f, b_out, tags, flags);
}

// Round 2
// 702.503 us; speedup vs baseline: 2.3074x; 2.3074x over previous
//
#include <hip/hip_runtime.h>
#include <hip/hip_bf16.h>

// Dims: B=64, T=512, V=512, H=256, O=512. M1 = B*T = 32768.
// d_in: sentence, prev_state, W_ih, b_ih, W_hh, b_hh, W_out, b_out
// d_out: tags [B,T,O] fp32 (16777216) then h_n [1,B,H] fp32 (16384)
//
// Round 2: PARTIAL fusion. Round-1 lesson: long-lived spin-waiting worker
// blocks (gemm3 gating) poisoned the RNN 4x — 252 agent-scope acquire
// spinners continuously invalidate every XCD's L2 and keep all 256 blocks
// resident (occupancy showed 23.6% for the full 1539us). Fix: workers do
// ONLY gemm1 tiles (no waits, ever) and exit; gemm3 is its own dispatch.
// The only spinners are the 4 rnn blocks' chunk gates (pre-satisfied after
// ~30us).

typedef __attribute__((ext_vector_type(8))) _Float16 half8;
typedef __attribute__((ext_vector_type(4))) _Float16 half4;
typedef __attribute__((ext_vector_type(4))) float   floatx4;

// LDS-only barrier: waits LDS ops, does NOT drain vmcnt — global loads/stores
// stay in flight across it.
__device__ __forceinline__ void lds_barrier() {
    asm volatile("s_waitcnt lgkmcnt(0)\n\ts_barrier" ::: "memory");
}

// Single-thread spin with backoff; capped so a logic bug fails verification
// instead of hanging the harness.
__device__ __forceinline__ void wait_ge(int* p, int need) {
    int spin = 0;
    while (__hip_atomic_load(p, __ATOMIC_ACQUIRE, __HIP_MEMORY_SCOPE_AGENT) < need) {
        __builtin_amdgcn_s_sleep(8);
        if (++spin > (1 << 22)) break;
    }
}

// ---------------- fp32 -> fp16 convert: W_ih and W_out in one launch ----------------
// wih_f (131072 halves) and wout_f (131072 halves) are contiguous in workspace.
__global__ void conv_weights(const float* __restrict__ wih, const float* __restrict__ wout,
                             _Float16* __restrict__ out) {
    int idx = blockIdx.x * blockDim.x + threadIdx.x;   // 0..65535 quads
    const float* src = (idx < 32768) ? wih : wout;
    int j = idx & 32767;
    float4 v = ((const float4*)src)[j];
    half4 h = { (_Float16)v.x, (_Float16)v.y, (_Float16)v.z, (_Float16)v.w };
    ((half4*)out)[idx] = h;
}

// ---------------- mega: gemm1 (exit-early workers) || rnn ----------------
__global__ __launch_bounds__(512, 2) void mega(
    const float* __restrict__ sentence,      // [32768,512] fp32
    const _Float16* __restrict__ wih,        // [256,512] f16
    const float* __restrict__ b_ih,
    const float* __restrict__ b_hh,
    float* __restrict__ xproj,               // [32768,256] fp32 (bias incl.)
    const float* __restrict__ h0g,           // [1,64,256] fp32
    const float* __restrict__ W_hh,          // [256,256] fp32
    _Float16* __restrict__ hid,              // [32768,256] f16 capped
    float* __restrict__ h_n,                 // [64,256] fp32
    int* __restrict__ flags)                 // [0..3] = g1done per 128-t chunk
{
    int* g1done = flags;   // gemm1 tiles finished per 128-t chunk (target 64)

    const int wave = threadIdx.x >> 6;
    const int lane = threadIdx.x & 63;
    const int row  = lane & 15;
    const int quad = lane >> 4;

    __shared__ _Float16 hb[2][16][264];

    if (blockIdx.x >= 4) {
        // ================= gemm1 worker role (blocks 4-255), NO WAITS =================
        int w = blockIdx.x - 4;   // 0..251
        const int K1 = 512, N1 = 256;
        for (int qq = w; qq < 256; qq += 252) {
            int chunk = qq >> 6;                 // chunk-0-first global order
            int item  = (qq & 63) * 4 + chunk;   // tile = (b, t-chunk)
            int m0 = item * 128 + wave * 16;

            floatx4 acc[16];
#pragma unroll
            for (int i = 0; i < 16; i++) acc[i] = (floatx4){0.f, 0.f, 0.f, 0.f};

            const float* pa = sentence + (size_t)(m0 + row) * K1 + quad * 8;
            for (int k0 = 0; k0 < K1; k0 += 32) {
                float4 a0 = *(const float4*)(pa + k0);
                float4 a1 = *(const float4*)(pa + k0 + 4);
                half8 a = { (_Float16)a0.x, (_Float16)a0.y, (_Float16)a0.z, (_Float16)a0.w,
                            (_Float16)a1.x, (_Float16)a1.y, (_Float16)a1.z, (_Float16)a1.w };
#pragma unroll
                for (int nt = 0; nt < 16; nt++) {
                    const _Float16* pb = wih + (size_t)(nt * 16 + row) * K1 + quad * 8 + k0;
                    half8 b = *(const half8*)pb;
                    acc[nt] = __builtin_amdgcn_mfma_f32_16x16x32_f16(a, b, acc[nt], 0, 0, 0);
                }
            }
#pragma unroll
            for (int nt = 0; nt < 16; nt++) {
                int n = nt * 16 + row;
                float bn = b_ih[n] + b_hh[n];
#pragma unroll
                for (int r = 0; r < 4; r++) {
                    int m = m0 + quad * 4 + r;
                    xproj[(size_t)m * N1 + n] = acc[nt][r] + bn;
                }
            }
            __threadfence();          // drain stores + L2 writeback (agent visibility)
            __syncthreads();          // all waves of the block done
            if (threadIdx.x == 0)
                __hip_atomic_fetch_add(&g1done[chunk], 1,
                                       __ATOMIC_RELEASE, __HIP_MEMORY_SCOPE_AGENT);
        }
        return;   // block retires; CU freed for the remaining RNN run
    }

    // ================= RNN role (blocks 0-3) =================
    const int Hh = 256, T = 512, LD = 264;
    int b0 = blockIdx.x * 16;
    int c = row;
    int q = quad;

    // W_hh fragments: wf[nt][kt], n = (wave*2+nt)*16 + c, k = kt*32 + q*8
    half8 wf[2][8];
#pragma unroll
    for (int nt = 0; nt < 2; nt++) {
        int n = (wave * 2 + nt) * 16 + c;
        const float* wr = W_hh + (size_t)n * Hh + q * 8;
#pragma unroll
        for (int kt = 0; kt < 8; kt++) {
            float4 x0 = *(const float4*)(wr + kt * 32);
            float4 x1 = *(const float4*)(wr + kt * 32 + 4);
            wf[nt][kt] = (half8){ (_Float16)x0.x, (_Float16)x0.y, (_Float16)x0.z, (_Float16)x0.w,
                                  (_Float16)x1.x, (_Float16)x1.y, (_Float16)x1.z, (_Float16)x1.w };
        }
    }

    for (int idx = threadIdx.x; idx < 16 * 256; idx += 512) {
        int m = idx >> 8, k = idx & 255;
        hb[0][m][k] = (_Float16)h0g[(size_t)(b0 + m) * Hh + k];
    }
    // Gate first prefetch (t=0,1) on gemm1 chunk 0; one spinner, then barrier
    // (also serves as the hb-fill barrier). Acquire load -> buffer_inv makes
    // the workers' xproj stores visible to this CU/XCD.
    if (threadIdx.x == 0) wait_ge(&g1done[0], 64);
    __syncthreads();

    const float* xpb = xproj + (size_t)(b0 + c) * T * Hh;
    _Float16* hidb = hid + (size_t)(b0 + c) * T * Hh;

    int noff[2];
#pragma unroll
    for (int nt = 0; nt < 2; nt++) noff[nt] = (wave * 2 + nt) * 16 + q * 4;

    // two prefetch slots: slot0 = even steps, slot1 = odd steps
    float4 xq0[2], xq1[2];
#pragma unroll
    for (int nt = 0; nt < 2; nt++) {
        xq0[nt] = *(const float4*)(xpb + (size_t)0 * Hh + noff[nt]);
        xq1[nt] = *(const float4*)(xpb + (size_t)1 * Hh + noff[nt]);
    }

    auto do_step = [&](int t, float4 (&xq)[2]) {
        const _Float16* hr = &hb[t & 1][0][0];
        // 4 independent chains: (nt=0,1) x (k-low, k-high), each 4 MFMAs deep
        floatx4 aA0 = {0.f,0.f,0.f,0.f}, aA1 = {0.f,0.f,0.f,0.f};
        floatx4 aB0 = {0.f,0.f,0.f,0.f}, aB1 = {0.f,0.f,0.f,0.f};
#pragma unroll
        for (int kt = 0; kt < 4; kt++) {
            half8 hfA = *(const half8*)(hr + c * LD + kt * 32 + q * 8);
            half8 hfB = *(const half8*)(hr + c * LD + (kt + 4) * 32 + q * 8);
            aA0 = __builtin_amdgcn_mfma_f32_16x16x32_f16(wf[0][kt],     hfA, aA0, 0, 0, 0);
            aB0 = __builtin_amdgcn_mfma_f32_16x16x32_f16(wf[0][kt + 4], hfB, aB0, 0, 0, 0);
            aA1 = __builtin_amdgcn_mfma_f32_16x16x32_f16(wf[1][kt],     hfA, aA1, 0, 0, 0);
            aB1 = __builtin_amdgcn_mfma_f32_16x16x32_f16(wf[1][kt + 4], hfB, aB1, 0, 0, 0);
        }
        floatx4 acc[2];
        acc[0] = aA0 + aB0;
        acc[1] = aA1 + aB1;

        _Float16* hw = &hb[(t + 1) & 1][0][0];
#pragma unroll
        for (int nt = 0; nt < 2; nt++) {
            float v0 = fmaxf(acc[nt][0] + xq[nt].x, 0.f);
            float v1 = fmaxf(acc[nt][1] + xq[nt].y, 0.f);
            float v2 = fmaxf(acc[nt][2] + xq[nt].z, 0.f);
            float v3 = fmaxf(acc[nt][3] + xq[nt].w, 0.f);
            half4 hv = { (_Float16)v0, (_Float16)v1, (_Float16)v2, (_Float16)v3 };
            *(half4*)(hw + c * LD + noff[nt]) = hv;                       // next step's B source
            half4 hc = { (_Float16)fminf(v0, 1.f), (_Float16)fminf(v1, 1.f),
                         (_Float16)fminf(v2, 1.f), (_Float16)fminf(v3, 1.f) };
            *(half4*)(hidb + (size_t)t * Hh + noff[nt]) = hc;             // capped hidden for GEMM3
            if (t == T - 1) {
                float4 hn = { v0, v1, v2, v3 };
                *(float4*)(h_n + (size_t)(b0 + c) * Hh + noff[nt]) = hn;
            }
        }
        int tp = (t + 2 < T) ? t + 2 : T - 1;
        // crossing into a new 128-t xproj chunk: tp in {128,129,256,257,384,385}
        if ((tp & 126) == 0) {
            if (threadIdx.x == 0) wait_ge(&g1done[tp >> 7], 64);
            __syncthreads();
        }
#pragma unroll
        for (int nt = 0; nt < 2; nt++)
            xq[nt] = *(const float4*)(xpb + (size_t)tp * Hh + noff[nt]);

        lds_barrier();   // LDS-only: global loads/stores remain in flight
    };

    for (int t = 0; t < T; t += 2) {
        do_step(t,     xq0);
        do_step(t + 1, xq1);
    }
}

// ---------------- GEMM3: tags = sigmoid(hid f16 [32768,256] @ W_out^T + b_out) -> fp32 [32768,512]
__global__ __launch_bounds__(256) void gemm3_tags(const _Float16* __restrict__ A,
                                                  const _Float16* __restrict__ Bw,   // W_out f16 [512,256]
                                                  const float* __restrict__ bias,
                                                  float* __restrict__ C) {
    const int K = 256, N = 512;
    int wave = threadIdx.x >> 6;
    int lane = threadIdx.x & 63;
    int row  = lane & 15;
    int quad = lane >> 4;
    int m0 = blockIdx.x * 64 + wave * 16;
    int n_base = blockIdx.y * 256;

    floatx4 acc[16];
#pragma unroll
    for (int i = 0; i < 16; i++) acc[i] = (floatx4){0.f, 0.f, 0.f, 0.f};

    const _Float16* pa = A + (size_t)(m0 + row) * K + quad * 8;
    for (int k0 = 0; k0 < K; k0 += 32) {
        half8 a = *(const half8*)(pa + k0);
#pragma unroll
        for (int nt = 0; nt < 16; nt++) {
            const _Float16* pb = Bw + (size_t)(n_base + nt * 16 + row) * K + quad * 8 + k0;
            half8 b = *(const half8*)pb;
            acc[nt] = __builtin_amdgcn_mfma_f32_16x16x32_f16(a, b, acc[nt], 0, 0, 0);
        }
    }
#pragma unroll
    for (int nt = 0; nt < 16; nt++) {
        int n = n_base + nt * 16 + row;
        float bn = bias[n];
#pragma unroll
        for (int r = 0; r < 4; r++) {
            int m = m0 + quad * 4 + r;
            float v = acc[nt][r] + bn;
            C[(size_t)m * N + n] = 1.f / (1.f + __expf(-v));
        }
    }
}

extern "C" void kernel_launch(void* const* d_in, const int* in_sizes, int n_in,
                              void* d_out, int out_size, void* d_ws, size_t ws_size,
                              hipStream_t stream) {
    const float* sentence   = (const float*)d_in[0];  // [64,512,512]
    const float* prev_state = (const float*)d_in[1];  // [1,64,256]
    const float* W_ih       = (const float*)d_in[2];  // [256,512]
    const float* b_ih       = (const float*)d_in[3];  // [256]
    const float* W_hh       = (const float*)d_in[4];  // [256,256]
    const float* b_hh       = (const float*)d_in[5];  // [256]
    const float* W_out      = (const float*)d_in[6];  // [512,256]
    const float* b_out      = (const float*)d_in[7];  // [512]

    const size_t WIH_N   = 256u * 512u;
    const size_t WOUT_N  = 512u * 256u;
    const size_t XPROJ_N = 32768u * 256u;
    const size_t HID_N   = 64u * 512u * 256u;

    char* w = (char*)d_ws;
    _Float16* wih_f  = (_Float16*)w;  w += WIH_N * sizeof(_Float16);
    _Float16* wout_f = (_Float16*)w;  w += WOUT_N * sizeof(_Float16);
    float*    xproj  = (float*)w;     w += XPROJ_N * sizeof(float);
    _Float16* hid_f  = (_Float16*)w;  w += HID_N * sizeof(_Float16);
    int*      flags  = (int*)w;       w += 256;

    float* tags = (float*)d_out;
    float* h_n  = (float*)d_out + 16777216;

    hipMemsetAsync(flags, 0, 256, stream);

    // both f16 weight buffers in one launch (they are contiguous in ws)
    conv_weights<<<256, 256, 0, stream>>>(W_ih, W_out, wih_f);

    mega<<<256, 512, 0, stream>>>(sentence, wih_f, b_ih, b_hh, xproj,
                                  prev_state, W_hh, hid_f, h_n, flags);

    gemm3_tags<<<dim3(512, 2), 256, 0, stream>>>(hid_f, wout_f, b_out, tags);
}

// Round 3
// 515.349 us; speedup vs baseline: 3.1453x; 1.3632x over previous
//
#include <hip/hip_runtime.h>
#include <hip/hip_bf16.h>

// Dims: B=64, T=512, V=512, H=256, O=512. M1 = B*T = 32768.
// d_in: sentence, prev_state, W_ih, b_ih, W_hh, b_hh, W_out, b_out
// d_out: tags [B,T,O] fp32 (16777216) then h_n [1,B,H] fp32 (16384)
//
// Round 3: NO cross-kernel overlap (rounds 1-2 proved bulk GEMM traffic
// concurrent with the latency-bound RNN costs ~1:1). Instead: restore the
// round-0 RNN exactly, and fix the GEMMs' B-feed (guide Common-mistake #1):
// stage the weight slice in LDS via global_load_lds(16B) with pre-swizzled
// global source (c ^= (n&7)<<4) so fragment ds_read_b128 is 2 lanes/bank.

typedef __attribute__((ext_vector_type(8))) _Float16 half8;
typedef __attribute__((ext_vector_type(4))) _Float16 half4;
typedef __attribute__((ext_vector_type(4))) float   floatx4;

// LDS-only barrier: waits LDS ops, does NOT drain vmcnt — global loads/stores
// stay in flight across it.
__device__ __forceinline__ void lds_barrier() {
    asm volatile("s_waitcnt lgkmcnt(0)\n\ts_barrier" ::: "memory");
}

// ---------------- fp32 -> fp16 convert: W_ih and W_out in one launch ----------------
// wih_f (131072 halves) and wout_f (131072 halves) are contiguous in workspace.
__global__ void conv_weights(const float* __restrict__ wih, const float* __restrict__ wout,
                             _Float16* __restrict__ out) {
    int idx = blockIdx.x * blockDim.x + threadIdx.x;   // 0..65535 quads
    const float* src = (idx < 32768) ? wih : wout;
    int j = idx & 32767;
    float4 v = ((const float4*)src)[j];
    half4 h = { (_Float16)v.x, (_Float16)v.y, (_Float16)v.z, (_Float16)v.w };
    ((half4*)out)[idx] = h;
}

// Stage 256 LDS rows x 512 B from f16 weights, XOR-swizzled within each row.
// LDS dest is linear (global_load_lds requirement, m104); the swizzle is applied
// to the per-lane GLOBAL source address (m173). Row n at lds[n*512 + c] holds
// global halves src[n*rowStrideHalves + ((c ^ ((n&7)<<4)) >> 1)].
__device__ __forceinline__ void stage_weights_swz(const _Float16* __restrict__ src,
                                                  int rowStrideHalves,
                                                  _Float16* lds) {
    int wave = threadIdx.x >> 6;
    int lane = threadIdx.x & 63;
#pragma unroll
    for (int j = 0; j < 16; j++) {
        int Lb = j * 8192 + wave * 1024 + lane * 16;   // this lane's LDS byte
        int n  = Lb >> 9;
        int c  = Lb & 511;
        int cs = c ^ ((n & 7) << 4);
        const _Float16* g = src + (size_t)n * rowStrideHalves + (cs >> 1);
        // wave-uniform LDS base; HW adds lane*16
        _Float16* l = lds + (j * 8192 + wave * 1024) / 2;
        __builtin_amdgcn_global_load_lds((const __attribute__((address_space(1))) void*)g,
                                         (__attribute__((address_space(3))) void*)l,
                                         16, 0, 0);
    }
    asm volatile("s_waitcnt vmcnt(0)" ::: "memory");
    __syncthreads();
}

// ---------------- GEMM1: xproj = sentence [32768,512] @ W_ih^T + (b_ih+b_hh) -> fp32 [B,T,H]
// 512 thr (8 waves), M-tile 128, full N=256, K split in two 128-KB LDS stages.
__global__ __launch_bounds__(512, 2) void gemm1_xproj(const float* __restrict__ A,      // sentence fp32
                                                      const _Float16* __restrict__ Bw,  // W_ih f16 [256,512]
                                                      const float* __restrict__ b_ih,
                                                      const float* __restrict__ b_hh,
                                                      float* __restrict__ C) {          // [32768,256]
    const int K = 512, N = 256;
    __shared__ _Float16 ldsB[65536];     // 256 rows x 256 halves (one K-half), 128 KB
    int wave = threadIdx.x >> 6;
    int lane = threadIdx.x & 63;
    int row  = lane & 15;
    int quad = lane >> 4;
    int m0 = blockIdx.x * 128 + wave * 16;

    floatx4 acc[16];
#pragma unroll
    for (int i = 0; i < 16; i++) acc[i] = (floatx4){0.f, 0.f, 0.f, 0.f};

    const float* pa = A + (size_t)(m0 + row) * K + quad * 8;
    const char* lb = (const char*)ldsB;

    for (int h = 0; h < 2; h++) {
        if (h) __syncthreads();                       // all waves done reading half 0
        stage_weights_swz(Bw + h * 256, 512, ldsB);   // wih[:, h*256 : h*256+256]

        for (int kk = 0; kk < 256; kk += 32) {
            float4 a0 = *(const float4*)(pa + h * 256 + kk);
            float4 a1 = *(const float4*)(pa + h * 256 + kk + 4);
            half8 a = { (_Float16)a0.x, (_Float16)a0.y, (_Float16)a0.z, (_Float16)a0.w,
                        (_Float16)a1.x, (_Float16)a1.y, (_Float16)a1.z, (_Float16)a1.w };
#pragma unroll
            for (int nt = 0; nt < 16; nt++) {
                int n = nt * 16 + row;
                int byte = n * 512 + ((quad * 16 + kk * 2) ^ ((n & 7) << 4));
                half8 b = *(const half8*)(lb + byte);
                acc[nt] = __builtin_amdgcn_mfma_f32_16x16x32_f16(a, b, acc[nt], 0, 0, 0);
            }
        }
    }
#pragma unroll
    for (int nt = 0; nt < 16; nt++) {
        int n = nt * 16 + row;
        float bn = b_ih[n] + b_hh[n];
#pragma unroll
        for (int r = 0; r < 4; r++) {
            int m = m0 + quad * 4 + r;
            C[(size_t)m * N + n] = acc[nt][r] + bn;
        }
    }
}

// ---------------- Recurrence (MFMA): EXACT round-0 kernel. 4 blocks x 16 batch rows,
// 512 threads (8 waves, 2/SIMD). 2 waves/SIMD restores TLP (m114).
__global__ __launch_bounds__(512, 2) void rnn_recur(const float* __restrict__ xp,    // [B,T,H] fp32 (bias incl.)
                                                    const float* __restrict__ h0,    // [1,B,H] fp32
                                                    const float* __restrict__ W_hh,  // [H,H] fp32
                                                    _Float16* __restrict__ hid,      // f16 [B,T,H] capped
                                                    float* __restrict__ h_n) {       // [B,H] fp32
    const int Hh = 256, T = 512, LD = 264;   // LDS row stride in halves
    int b0   = blockIdx.x * 16;
    int wave = threadIdx.x >> 6;
    int lane = threadIdx.x & 63;
    int c    = lane & 15;       // batch col within tile
    int q    = lane >> 4;

    half8 wf[2][8];
#pragma unroll
    for (int nt = 0; nt < 2; nt++) {
        int n = (wave * 2 + nt) * 16 + c;
        const float* wr = W_hh + (size_t)n * Hh + q * 8;
#pragma unroll
        for (int kt = 0; kt < 8; kt++) {
            float4 x0 = *(const float4*)(wr + kt * 32);
            float4 x1 = *(const float4*)(wr + kt * 32 + 4);
            wf[nt][kt] = (half8){ (_Float16)x0.x, (_Float16)x0.y, (_Float16)x0.z, (_Float16)x0.w,
                                  (_Float16)x1.x, (_Float16)x1.y, (_Float16)x1.z, (_Float16)x1.w };
        }
    }

    __shared__ _Float16 hb[2][16][264];
    for (int idx = threadIdx.x; idx < 16 * 256; idx += 512) {
        int m = idx >> 8, k = idx & 255;
        hb[0][m][k] = (_Float16)h0[(size_t)(b0 + m) * Hh + k];
    }
    __syncthreads();   // once, before the loop

    const float* xpb = xp + (size_t)(b0 + c) * T * Hh;
    _Float16* hidb = hid + (size_t)(b0 + c) * T * Hh;

    int noff[2];
#pragma unroll
    for (int nt = 0; nt < 2; nt++) noff[nt] = (wave * 2 + nt) * 16 + q * 4;

    float4 xq0[2], xq1[2];
#pragma unroll
    for (int nt = 0; nt < 2; nt++) {
        xq0[nt] = *(const float4*)(xpb + (size_t)0 * Hh + noff[nt]);
        xq1[nt] = *(const float4*)(xpb + (size_t)1 * Hh + noff[nt]);
    }

    auto do_step = [&](int t, float4 (&xq)[2]) {
        const _Float16* hr = &hb[t & 1][0][0];
        floatx4 aA0 = {0.f,0.f,0.f,0.f}, aA1 = {0.f,0.f,0.f,0.f};
        floatx4 aB0 = {0.f,0.f,0.f,0.f}, aB1 = {0.f,0.f,0.f,0.f};
#pragma unroll
        for (int kt = 0; kt < 4; kt++) {
            half8 hfA = *(const half8*)(hr + c * LD + kt * 32 + q * 8);
            half8 hfB = *(const half8*)(hr + c * LD + (kt + 4) * 32 + q * 8);
            aA0 = __builtin_amdgcn_mfma_f32_16x16x32_f16(wf[0][kt],     hfA, aA0, 0, 0, 0);
            aB0 = __builtin_amdgcn_mfma_f32_16x16x32_f16(wf[0][kt + 4], hfB, aB0, 0, 0, 0);
            aA1 = __builtin_amdgcn_mfma_f32_16x16x32_f16(wf[1][kt],     hfA, aA1, 0, 0, 0);
            aB1 = __builtin_amdgcn_mfma_f32_16x16x32_f16(wf[1][kt + 4], hfB, aB1, 0, 0, 0);
        }
        floatx4 acc[2];
        acc[0] = aA0 + aB0;
        acc[1] = aA1 + aB1;

        _Float16* hw = &hb[(t + 1) & 1][0][0];
#pragma unroll
        for (int nt = 0; nt < 2; nt++) {
            float v0 = fmaxf(acc[nt][0] + xq[nt].x, 0.f);
            float v1 = fmaxf(acc[nt][1] + xq[nt].y, 0.f);
            float v2 = fmaxf(acc[nt][2] + xq[nt].z, 0.f);
            float v3 = fmaxf(acc[nt][3] + xq[nt].w, 0.f);
            half4 hv = { (_Float16)v0, (_Float16)v1, (_Float16)v2, (_Float16)v3 };
            *(half4*)(hw + c * LD + noff[nt]) = hv;                       // next step's B source
            half4 hc = { (_Float16)fminf(v0, 1.f), (_Float16)fminf(v1, 1.f),
                         (_Float16)fminf(v2, 1.f), (_Float16)fminf(v3, 1.f) };
            *(half4*)(hidb + (size_t)t * Hh + noff[nt]) = hc;             // capped hidden for GEMM3
            if (t == T - 1) {
                float4 hn = { v0, v1, v2, v3 };
                *(float4*)(h_n + (size_t)(b0 + c) * Hh + noff[nt]) = hn;
            }
        }
        int tp = (t + 2 < T) ? t + 2 : T - 1;
#pragma unroll
        for (int nt = 0; nt < 2; nt++)
            xq[nt] = *(const float4*)(xpb + (size_t)tp * Hh + noff[nt]);

        lds_barrier();   // LDS-only: global loads/stores remain in flight
    };

    for (int t = 0; t < T; t += 2) {
        do_step(t,     xq0);
        do_step(t + 1, xq1);
    }
}

// ---------------- GEMM3: tags = sigmoid(hid f16 [32768,256] @ W_out^T + b_out) -> fp32 [32768,512]
// 512 thr (8 waves), M-tile 128, N-half 256 per block (W_out slice 128 KB in LDS).
__global__ __launch_bounds__(512, 2) void gemm3_tags(const _Float16* __restrict__ A,
                                                     const _Float16* __restrict__ Bw,   // W_out f16 [512,256]
                                                     const float* __restrict__ bias,
                                                     float* __restrict__ C) {
    const int K = 256, N = 512;
    __shared__ _Float16 ldsB[65536];     // 256 rows x 256 halves, 128 KB
    int wave = threadIdx.x >> 6;
    int lane = threadIdx.x & 63;
    int row  = lane & 15;
    int quad = lane >> 4;
    int m0 = blockIdx.x * 128 + wave * 16;
    int nb = blockIdx.y;                 // N-half

    stage_weights_swz(Bw + (size_t)nb * 256 * K, K, ldsB);   // W_out[nb*256 .. +256)

    floatx4 acc[16];
#pragma unroll
    for (int i = 0; i < 16; i++) acc[i] = (floatx4){0.f, 0.f, 0.f, 0.f};

    const _Float16* pa = A + (size_t)(m0 + row) * K + quad * 8;
    const char* lb = (const char*)ldsB;

    for (int kk = 0; kk < 256; kk += 32) {
        half8 a = *(const half8*)(pa + kk);
#pragma unroll
        for (int nt = 0; nt < 16; nt++) {
            int n = nt * 16 + row;
            int byte = n * 512 + ((quad * 16 + kk * 2) ^ ((n & 7) << 4));
            half8 b = *(const half8*)(lb + byte);
            acc[nt] = __builtin_amdgcn_mfma_f32_16x16x32_f16(a, b, acc[nt], 0, 0, 0);
        }
    }
#pragma unroll
    for (int nt = 0; nt < 16; nt++) {
        int n = nb * 256 + nt * 16 + row;
        float bn = bias[n];
#pragma unroll
        for (int r = 0; r < 4; r++) {
            int m = m0 + quad * 4 + r;
            float v = acc[nt][r] + bn;
            C[(size_t)m * N + n] = 1.f / (1.f + __expf(-v));
        }
    }
}

extern "C" void kernel_launch(void* const* d_in, const int* in_sizes, int n_in,
                              void* d_out, int out_size, void* d_ws, size_t ws_size,
                              hipStream_t stream) {
    const float* sentence   = (const float*)d_in[0];  // [64,512,512]
    const float* prev_state = (const float*)d_in[1];  // [1,64,256]
    const float* W_ih       = (const float*)d_in[2];  // [256,512]
    const float* b_ih       = (const float*)d_in[3];  // [256]
    const float* W_hh       = (const float*)d_in[4];  // [256,256]
    const float* b_hh       = (const float*)d_in[5];  // [256]
    const float* W_out      = (const float*)d_in[6];  // [512,256]
    const float* b_out      = (const float*)d_in[7];  // [512]

    const size_t WIH_N   = 256u * 512u;
    const size_t WOUT_N  = 512u * 256u;
    const size_t XPROJ_N = 32768u * 256u;
    const size_t HID_N   = 64u * 512u * 256u;

    char* w = (char*)d_ws;
    _Float16* wih_f  = (_Float16*)w;  w += WIH_N * sizeof(_Float16);
    _Float16* wout_f = (_Float16*)w;  w += WOUT_N * sizeof(_Float16);
    float*    xproj  = (float*)w;     w += XPROJ_N * sizeof(float);
    _Float16* hid_f  = (_Float16*)w;  w += HID_N * sizeof(_Float16);

    float* tags = (float*)d_out;
    float* h_n  = (float*)d_out + 16777216;

    // both f16 weight buffers in one launch (they are contiguous in ws)
    conv_weights<<<256, 256, 0, stream>>>(W_ih, W_out, wih_f);

    gemm1_xproj<<<256, 512, 0, stream>>>(sentence, wih_f, b_ih, b_hh, xproj);

    rnn_recur<<<4, 512, 0, stream>>>(xproj, prev_state, W_hh, hid_f, h_n);

    gemm3_tags<<<dim3(256, 2), 512, 0, stream>>>(hid_f, wout_f, b_out, tags);
}